// Round 2
// baseline (210.822 us; speedup 1.0000x reference)
//
#include <hip/hip_runtime.h>
#include <math.h>

// PCE basis expansion: Phi[n,b] = prod_j polyval(xn[n,j], idxset[b,j])
// D=50, P=2. Output 32768x1326 fp32 = 174 MB -> write-BW floor ~26 us.
//
// R3: run-aligned vectorized LDS reads. The order-2 block is a sequence of
// "runs": for q=0..49 (a = 49-q), run q = [H1(a)H1(x49), H1(a)H1(x48), ...,
// H1(a)H1(a+1), H2(a)], laid out innermost-dim-first (verified against the
// indexset() recursion; run q starts at col 51 + q(q+1)/2, length q+1).
// Storing H1 REVERSED (rev[k] = H1(x_{49-k})) makes every run's varying
// factors ascending-contiguous FROM OFFSET 0 -> groups of 4 columns within
// a run read all 4 varying factors with ONE aligned ds_read_b128, plus a
// quasi-broadcast scalar read of the shared factor rev[q]. The H2 element
// (last of each run) is patched in via a precomputed lane-constant select.
// Per 4 outputs: 3 LDS instrs, conflict-free (was 8 scalar reads at 4-way
// conflict). Stores are scalar dwords (always aligned, coalesced-enough for
// L2 merge). All work-unit decode is closed-form, once per thread.

#define DD     50
#define NBASIS 1326
#define BN     16
#define BLOCK  256
#define RS     104        // LDS row stride in floats (416 B, 16B-aligned)
#define ONEOFF 52         // T[r][52] = 1.0 (identity factor slot)
#define H2OFF  54         // T[r][54+q] = H2(x_{49-q})
#define NUNITS 352        // 12 (order1 f4) + 1 (order1 tail) + 1 (col0) + 338 (order2)

__global__ __launch_bounds__(BLOCK) void pce_kernel(
    const float* __restrict__ x, const float* __restrict__ mean,
    const float* __restrict__ var, const float* __restrict__ basis,
    float* __restrict__ out, int n)
{
    __shared__ __align__(16) float T[BN][RS];   // 6.7 KB
    const int tid  = threadIdx.x;
    const int row0 = blockIdx.x * BN;

    // Hermite basis coefficients (broadcast loads, cached)
    float b10 = basis[3], b11 = basis[4], b12 = basis[5];
    float b20 = basis[6], b21 = basis[7], b22 = basis[8];

    // ---- Decode this thread's <=2 work units (closed form, once) ----
    // unit u: 0..11   order-1 group: cols 1+4u..4+4u  = rev[4u..4u+3]
    //         12      order-1 tail : cols 49,50       = rev[48],rev[49]
    //         13      col 0 = 1.0
    //         14..351 order-2: u2=u-14 -> (q,j); cols 51+q(q+1)/2+4j ..
    //                 values rev[q]*rev[4j+e], except element t==q -> H2[q]
    int cols0[2], e0[2], f0off[2], hoff[2], hq[2], nval[2];
    #pragma unroll
    for (int s = 0; s < 2; ++s) {
        int u = tid + s * BLOCK;
        int C0 = 0, E0 = ONEOFF, F0 = ONEOFF, HO = ONEOFF, HQ = -1, NV = 1;
        if (u < 12) {
            C0 = 1 + 4 * u; E0 = 4 * u; NV = 4;
        } else if (u == 12) {
            C0 = 49; E0 = 48; NV = 2;
        } else if (u == 13) {
            C0 = 0; E0 = ONEOFF; NV = 1;
        } else if (u < NUNITS) {
            int u2 = u - 14;
            // groups-of-4 cumulative: cum(q=4m) = 2m(m+1); invert
            int m = (int)((sqrtf((float)(2 * u2) + 1.0f) - 1.0f) * 0.5f);
            while (2 * (m + 1) * (m + 2) <= u2) ++m;
            while (m > 0 && 2 * m * (m + 1) > u2) --m;
            int rem  = u2 - 2 * m * (m + 1);
            int qoff = rem / (m + 1);
            int j    = rem - qoff * (m + 1);
            int q    = 4 * m + qoff;
            C0 = 51 + (q * (q + 1)) / 2 + 4 * j;
            E0 = 4 * j;
            F0 = q;
            HO = H2OFF + q;
            HQ = q - 4 * j; if (HQ > 3) HQ = -1;   // H2 element in this group?
            NV = q + 1 - 4 * j; if (NV > 4) NV = 4;
        }
        cols0[s] = C0; e0[s] = E0; f0off[s] = F0;
        hoff[s] = HO; hq[s] = HQ; nval[s] = NV;
    }
    const bool has2 = (tid < NUNITS - BLOCK);   // tid < 96

    // ---- Stage per-row reversed H1/H2 tables (coalesced x reads) ----
    for (int i = tid; i < BN * DD; i += BLOCK) {
        int r = i / DD, c = i - r * DD;
        float xv = (x[(size_t)(row0 + r) * DD + c] - mean[c]) / var[c];
        float x2 = xv * xv;
        int k = (DD - 1) - c;                    // reversed dim index
        T[r][k]         = b10 + b11 * xv + b12 * x2;   // H1
        T[r][H2OFF + k] = b20 + b21 * xv + b22 * x2;   // H2
    }
    if (tid < BN) {                              // identity slot + pads
        T[tid][50] = 0.0f; T[tid][51] = 0.0f;
        T[tid][ONEOFF] = 1.0f; T[tid][53] = 0.0f;
    }
    __syncthreads();

    // ---- Emit: 16 rows x (1-2 units) ----
    #pragma unroll
    for (int r = 0; r < BN; ++r) {
        float* o = out + (size_t)(row0 + r) * NBASIS;
        {
            float4 v  = *(const float4*)&T[r][e0[0]];
            float  f0 = T[r][f0off[0]];
            float  h  = T[r][hoff[0]];
            float w0 = (hq[0] == 0) ? h : f0 * v.x;
            float w1 = (hq[0] == 1) ? h : f0 * v.y;
            float w2 = (hq[0] == 2) ? h : f0 * v.z;
            float w3 = (hq[0] == 3) ? h : f0 * v.w;
            float* p = o + cols0[0];
            p[0] = w0;
            if (nval[0] > 1) p[1] = w1;
            if (nval[0] > 2) p[2] = w2;
            if (nval[0] > 3) p[3] = w3;
        }
        if (has2) {
            float4 v  = *(const float4*)&T[r][e0[1]];
            float  f0 = T[r][f0off[1]];
            float  h  = T[r][hoff[1]];
            float w0 = (hq[1] == 0) ? h : f0 * v.x;
            float w1 = (hq[1] == 1) ? h : f0 * v.y;
            float w2 = (hq[1] == 2) ? h : f0 * v.z;
            float w3 = (hq[1] == 3) ? h : f0 * v.w;
            float* p = o + cols0[1];
            p[0] = w0;
            if (nval[1] > 1) p[1] = w1;
            if (nval[1] > 2) p[2] = w2;
            if (nval[1] > 3) p[3] = w3;
        }
    }
}

extern "C" void kernel_launch(void* const* d_in, const int* in_sizes, int n_in,
                              void* d_out, int out_size, void* d_ws, size_t ws_size,
                              hipStream_t stream) {
    const float* x     = (const float*)d_in[0];
    const float* mean  = (const float*)d_in[1];
    const float* var   = (const float*)d_in[2];
    const float* basis = (const float*)d_in[3];
    float* out = (float*)d_out;

    const int d = in_sizes[1];          // 50
    const int n = in_sizes[0] / d;      // 32768

    (void)d_ws; (void)ws_size;          // workspace intentionally unused

    pce_kernel<<<(n + BN - 1) / BN, BLOCK, 0, stream>>>(x, mean, var, basis, out, n);
}

// Round 3
// 184.144 us; speedup vs baseline: 1.1449x; 1.1449x over previous
//
#include <hip/hip_runtime.h>
#include <math.h>

// PCE basis expansion: Phi[n,b] = prod_j polyval(xn[n,j], idxset[b,j])
// D=50, P=2. Output 32768x1326 fp32 = 174 MB -> write-BW floor ~26 us.
//
// R4 = R2's emit/store structure (the proven one: lane <-> column PAIR,
// float2 stores at orow[tid] -> 512B/wave contiguous) + R3's conflict-free
// LDS layout. R3's regression (210 us) was the scalar strided stores, NOT
// the layout. Here only the LDS READ side changes vs R2:
//   rev[k] = H1(x_{49-k}) contiguous (stride-1)  -> adjacent lanes' varying
//   factors stride 2 floats = 2-way bank aliasing = FREE (vs 4-way at the
//   old dim*3+ord interleave); shared factor rev[q] and H2 reads are
//   same-address broadcasts within a run.
// Column -> (off0,off1) closed form (verified in R3, absmax 0):
//   c==0        -> 1.0            (ONEOFF,ONEOFF)
//   1<=c<=50    -> rev[c-1]       (c-1, ONEOFF)
//   c>=51, t=c-51, q=trinv(t), s=t-T(q):
//     s==q      -> H2[q]          (H2OFF+q, ONEOFF)
//     else      -> rev[s]*rev[q]  (s, q)

#define DD     50
#define NBASIS 1326
#define NPAIR  (NBASIS / 2)   // 663
#define BN     16
#define BLOCK  256
#define RS     104            // LDS row stride in floats
#define ONEOFF 52             // T[r][52] = 1.0 (identity factor slot)
#define H2OFF  54             // T[r][54+q] = H2(x_{49-q})

__device__ __forceinline__ int col_desc(int c) {
    if (c == 0) return ONEOFF | (ONEOFF << 8);
    if (c <= DD) return (c - 1) | (ONEOFF << 8);      // rev[c-1] * 1.0
    int t = c - (DD + 1);                             // index in order-2 block
    int q = (int)((sqrtf((float)(8 * t + 1)) - 1.0f) * 0.5f);
    while ((q + 1) * (q + 2) / 2 <= t) ++q;           // exact fix-up
    while (q * (q + 1) / 2 > t) --q;
    int s = t - q * (q + 1) / 2;                      // position within run q
    if (s == q) return (H2OFF + q) | (ONEOFF << 8);   // H2(x_{49-q}) * 1.0
    return s | (q << 8);                              // rev[s] * rev[q]
}

__global__ __launch_bounds__(BLOCK) void pce_kernel(
    const float* __restrict__ x, const float* __restrict__ mean,
    const float* __restrict__ var, const float* __restrict__ basis,
    float* __restrict__ out, int n)
{
    __shared__ float T[BN][RS];   // 16 x 104 floats = 6.5 KB
    const int tid  = threadIdx.x;
    const int row0 = blockIdx.x * BN;

    // Hermite basis coefficients (broadcast loads, cached)
    float b10 = basis[3], b11 = basis[4], b12 = basis[5];
    float b20 = basis[6], b21 = basis[7], b22 = basis[8];

    // Per-thread descriptors: 3 column-pair slots, computed ONCE in registers.
    const int p0 = tid, p1 = tid + BLOCK, p2 = tid + 2 * BLOCK;
    const bool has2 = (p2 < NPAIR);                   // tid < 151
    int2 dA = make_int2(col_desc(2 * p0), col_desc(2 * p0 + 1));
    int2 dB = make_int2(col_desc(2 * p1), col_desc(2 * p1 + 1));
    int2 dC = has2 ? make_int2(col_desc(2 * p2), col_desc(2 * p2 + 1))
                   : make_int2(ONEOFF, ONEOFF);

    // Stage per-row reversed H1/H2 tables (coalesced x reads).
    for (int i = tid; i < BN * DD; i += BLOCK) {
        int r = i / DD, c = i - r * DD;
        float xv = (x[(size_t)(row0 + r) * DD + c] - mean[c]) / var[c];
        float x2 = xv * xv;
        int k = (DD - 1) - c;                         // reversed dim index
        T[r][k]         = b10 + b11 * xv + b12 * x2;  // H1
        T[r][H2OFF + k] = b20 + b21 * xv + b22 * x2;  // H2
    }
    if (tid < BN) T[tid][ONEOFF] = 1.0f;              // identity factor
    __syncthreads();

    // Emit: identical structure to R2 (float2 at orow[tid] -> 512B/wave).
    #pragma unroll
    for (int r = 0; r < BN; ++r) {
        const float* pvr = T[r];
        float2* orow = (float2*)(out + (size_t)(row0 + r) * NBASIS); // 5304%8==0
        float2 v;
        v.x = pvr[dA.x & 0xff] * pvr[dA.x >> 8];
        v.y = pvr[dA.y & 0xff] * pvr[dA.y >> 8];
        orow[p0] = v;
        v.x = pvr[dB.x & 0xff] * pvr[dB.x >> 8];
        v.y = pvr[dB.y & 0xff] * pvr[dB.y >> 8];
        orow[p1] = v;
        if (has2) {
            v.x = pvr[dC.x & 0xff] * pvr[dC.x >> 8];
            v.y = pvr[dC.y & 0xff] * pvr[dC.y >> 8];
            orow[p2] = v;
        }
    }
}

extern "C" void kernel_launch(void* const* d_in, const int* in_sizes, int n_in,
                              void* d_out, int out_size, void* d_ws, size_t ws_size,
                              hipStream_t stream) {
    const float* x     = (const float*)d_in[0];
    const float* mean  = (const float*)d_in[1];
    const float* var   = (const float*)d_in[2];
    const float* basis = (const float*)d_in[3];
    float* out = (float*)d_out;

    const int d = in_sizes[1];          // 50
    const int n = in_sizes[0] / d;      // 32768

    (void)d_ws; (void)ws_size;          // workspace intentionally unused

    pce_kernel<<<(n + BN - 1) / BN, BLOCK, 0, stream>>>(x, mean, var, basis, out, n);
}